// Round 15
// baseline (290.772 us; speedup 1.0000x reference)
//
#include <hip/hip_runtime.h>
#include <hip/hip_bf16.h>

// GCN 2-layer on MI355X — global-atomic-free CSR build + register-acc aggregation.
// R5-R15: see git history. agg1 FROZEN at 89us = HW wall (random 128B
//      gathers, 12.8MB table, L2-miss path 3.4 TB/s; 9x reproduced).
// R16-R19: QUARTERING ARC abandoned (L2-resident 32B gathers lose).
// R20: nontemporal store REGRESSED +58us. Reverted.
// R21: pipelined k_gemm, grid 512. 313us.
// R22: k_part LDS-staged counting sort. 302.6us.
// R23: harness ws-poison fill = 42us/iter; launch boundary ~3-7us.
// R24: merged detect+prep, eliminated scanB. 297.8us.
// R25/R26: block-local part + binary-search sort2 REGRESSED; measured
//      sort2 srcSorted scatter = 95MB writes for 12.8MB payload.
// R27: sort2 output staged in 96KB dynamic LDS (1.0x write amp). 286.2us.
// R28: int4 edge loads in hist/part (G13). 284.2us BEST.
// R29: (a) fold detect+prep INTO k_hist (every block recomputes the cheap
//      64-load detect inline; block 0 publishes flags, block 1 does weight
//      prep) -> -1 dispatch boundary (R23/R24-proven ~3-7us each).
//      (b) gemm grid 512->768: R5 counters showed occupancy 24.6% = the
//      2-blocks/CU grid cap (VGPR allows 3); waves still run >=2 rbs so
//      the R21 pipeline stays engaged. Everything else byte-identical.

typedef short s8_t __attribute__((ext_vector_type(8)));
typedef float f4_t __attribute__((ext_vector_type(4)));

__device__ __forceinline__ float bf2f(unsigned short u) {
    union { unsigned int u; float f; } c; c.u = ((unsigned int)u) << 16; return c.f;
}
__device__ __forceinline__ unsigned short f2bf(float f) {
    union { float f; unsigned int u; } c; c.f = f;
    unsigned int u = c.u;
    unsigned int r = (u + 0x7fffu + ((u >> 16) & 1u)) >> 16;  // round-nearest-even
    return (unsigned short)r;
}
__device__ __forceinline__ float loadF(const void* p, int i, int isbf) {
    return isbf ? bf2f(((const unsigned short*)p)[i]) : ((const float*)p)[i];
}
__device__ __forceinline__ int edgeIdx(const void* e, long long i, int is64) {
    return is64 ? (int)((const long long*)e)[i] : ((const int*)e)[i];
}
// R28: load 4 consecutive edge indices starting at element i (i % 4 == 0).
__device__ __forceinline__ void edgeIdx4(const void* e, long long i, int is64,
                                         int& v0, int& v1, int& v2, int& v3) {
    if (is64) {
        const int4* p = (const int4*)((const long long*)e + i);
        int4 a = p[0], b = p[1];           // 2 long longs per int4 (LE: low word = .x/.z)
        v0 = a.x; v1 = a.z; v2 = b.x; v3 = b.z;
    } else {
        int4 v = *(const int4*)((const int*)e + i);
        v0 = v.x; v1 = v.y; v2 = v.z; v3 = v.w;
    }
}

// R29: hist + inline detect + (block 1) weight prep.
// Every block recomputes detect from e[0..64)/x[0..64) (L2-hot, ~free);
// block 0 publishes flags for downstream kernels; block 1 preps weights.
__launch_bounds__(256)
__global__ void k_hist(const void* e, const void* x, const void* W1,
                       int* flags, unsigned short* __restrict__ wT,
                       unsigned short* __restrict__ wTh,
                       unsigned short* __restrict__ wTl,
                       int* __restrict__ histT, int E, int B, int HB) {
    __shared__ int hist[1024];
    __shared__ int sdet[2];
    int tid = threadIdx.x;
    if (tid < 64) {
        unsigned int ew = ((const unsigned int*)e)[2 * tid + 1];
        unsigned long long nz = __ballot(ew != 0);
        unsigned int xw = ((const unsigned int*)x)[tid];
        unsigned int low = xw & 0xffffu;
        unsigned int e8 = (low >> 7) & 0xffu;
        bool plaus = (low == 0u) || (e8 >= 110u && e8 <= 135u);
        unsigned long long pl = __ballot(plaus);
        if (tid == 0) {
            sdet[0] = (nz == 0ull) ? 1 : 0;
            sdet[1] = (__popcll(pl) > 32) ? 1 : 0;
            if (blockIdx.x == 0) { flags[0] = sdet[0]; flags[1] = sdet[1]; }
        }
    }
    for (int f = tid; f < B; f += 256) hist[f] = 0;
    __syncthreads();
    int is64 = sdet[0];
    int isbf = sdet[1];
    if (blockIdx.x == 1) {   // weight prep (one block; others hist in parallel)
        if (isbf) {
            const unsigned short* w = (const unsigned short*)W1;
            for (int idx = tid; idx < 128 * 64; idx += 256) {
                int k = idx >> 6, n = idx & 63;
                wT[n * 128 + k] = w[idx];
            }
        } else {
            const float* w = (const float*)W1;
            for (int idx = tid; idx < 128 * 64; idx += 256) {
                int k = idx >> 6, n = idx & 63;
                float v = w[idx];
                unsigned short h = f2bf(v);
                wTh[n * 128 + k] = h;
                wTl[n * 128 + k] = f2bf(v - bf2f(h));
            }
        }
    }
    int base = blockIdx.x * 4096;
    if (base + 4096 <= E) {
        #pragma unroll
        for (int k4 = 0; k4 < 4; ++k4) {
            int i = base + (k4 * 256 + tid) * 4;
            int d0, d1, d2, d3;
            edgeIdx4(e, (long long)E + i, is64, d0, d1, d2, d3);
            atomicAdd(&hist[d0 >> 9], 1);
            atomicAdd(&hist[d1 >> 9], 1);
            atomicAdd(&hist[d2 >> 9], 1);
            atomicAdd(&hist[d3 >> 9], 1);
        }
    } else {
        #pragma unroll
        for (int k = 0; k < 16; ++k) {
            int i = base + k * 256 + tid;
            if (i < E) {
                int d = edgeIdx(e, (long long)E + i, is64);
                atomicAdd(&hist[d >> 9], 1);
            }
        }
    }
    __syncthreads();
    for (int f = tid; f < B; f += 256)
        histT[(long long)f * HB + blockIdx.x] = hist[f];
}

// Exclusive scan over M = B*HB ints, level A. partial[b] = block sum (raw).
__global__ void k_scanA(int* __restrict__ data, int* __restrict__ partial, int M) {
    __shared__ int s[256];
    int tid = threadIdx.x;
    int i = blockIdx.x * 256 + tid;
    int v = (i < M) ? data[i] : 0;
    s[tid] = v; __syncthreads();
    for (int off = 1; off < 256; off <<= 1) {
        int t = (tid >= off) ? s[tid - off] : 0;
        __syncthreads(); s[tid] += t; __syncthreads();
    }
    if (i < M) data[i] = s[tid] - v;
    if (tid == 255) partial[blockIdx.x] = s[255];
}

// R24 level C (scanB eliminated): each block recomputes its own base =
// sum(partial[0..bb)) via strided loads + LDS tree reduce (<=599 ints),
// then adds it and extracts bucketStart.
__global__ void k_scanC(int* __restrict__ data, const int* __restrict__ partial,
                        int* __restrict__ bucketStart, int M, int HB, int B, int E) {
    __shared__ int red[256];
    int tid = threadIdx.x;
    int bb = blockIdx.x;
    int s = 0;
    for (int j = tid; j < bb; j += 256) s += partial[j];
    red[tid] = s; __syncthreads();
    for (int off = 128; off > 0; off >>= 1) {
        if (tid < off) red[tid] += red[tid + off];
        __syncthreads();
    }
    int base = red[0];
    int f = bb * 256 + tid;
    if (f < M) {
        int val = data[f] + base;
        data[f] = val;
        int q = f / HB;
        if (f - q * HB == 0) bucketStart[q] = val;
    }
    if (f == 0) bucketStart[B] = E;
}

// Partition (R22): LDS-staged counting sort per block.
// R28: int4 src+dst loads (4 edges / 2 instrs) on full blocks.
// part[pos] = src | (dstLocal << 17)   (requires N <= 2^17).
__launch_bounds__(256)
__global__ void k_part(const void* e, const int* __restrict__ histT,
                       int* __restrict__ part, const int* flags,
                       int E, int B, int HB) {
    __shared__ int lcur[1024];          // global scanned base per bucket
    __shared__ int lcnt[1024];          // local count -> local start (in place)
    __shared__ int sc[256];             // scan partials
    __shared__ int buf[4096];           // staged edge words
    __shared__ unsigned short bkt[4096];// bucket id per staged slot
    int tid = threadIdx.x;
    int is64 = flags[0];
    for (int f = tid; f < 1024; f += 256) {
        lcur[f] = (f < B) ? histT[(long long)f * HB + blockIdx.x] : 0;
        lcnt[f] = 0;
    }
    __syncthreads();
    int base = blockIdx.x * 4096;
    int val[16], bk[16], rk[16];
    if (base + 4096 <= E) {
        #pragma unroll
        for (int k4 = 0; k4 < 4; ++k4) {
            int i = base + (k4 * 256 + tid) * 4;
            int s0, s1, s2, s3, d0, d1, d2, d3;
            edgeIdx4(e, (long long)i, is64, s0, s1, s2, s3);
            edgeIdx4(e, (long long)E + i, is64, d0, d1, d2, d3);
            val[k4 * 4 + 0] = s0 | ((d0 & 511) << 17); bk[k4 * 4 + 0] = d0 >> 9;
            val[k4 * 4 + 1] = s1 | ((d1 & 511) << 17); bk[k4 * 4 + 1] = d1 >> 9;
            val[k4 * 4 + 2] = s2 | ((d2 & 511) << 17); bk[k4 * 4 + 2] = d2 >> 9;
            val[k4 * 4 + 3] = s3 | ((d3 & 511) << 17); bk[k4 * 4 + 3] = d3 >> 9;
            rk[k4 * 4 + 0] = atomicAdd(&lcnt[bk[k4 * 4 + 0]], 1);
            rk[k4 * 4 + 1] = atomicAdd(&lcnt[bk[k4 * 4 + 1]], 1);
            rk[k4 * 4 + 2] = atomicAdd(&lcnt[bk[k4 * 4 + 2]], 1);
            rk[k4 * 4 + 3] = atomicAdd(&lcnt[bk[k4 * 4 + 3]], 1);
        }
    } else {
        #pragma unroll
        for (int k = 0; k < 16; ++k) {
            int i = base + k * 256 + tid;
            if (i < E) {
                int s = edgeIdx(e, i, is64);
                int d = edgeIdx(e, (long long)E + i, is64);
                val[k] = s | ((d & 511) << 17);
                bk[k] = d >> 9;
                rk[k] = atomicAdd(&lcnt[bk[k]], 1);
            } else {
                bk[k] = -1;
            }
        }
    }
    __syncthreads();
    // in-place exclusive scan of lcnt[0..1023] (4 elems/thread + 256-scan)
    int c0 = lcnt[4 * tid], c1 = lcnt[4 * tid + 1];
    int c2 = lcnt[4 * tid + 2], c3 = lcnt[4 * tid + 3];
    int tot = c0 + c1 + c2 + c3;
    sc[tid] = tot; __syncthreads();
    for (int off = 1; off < 256; off <<= 1) {
        int t = (tid >= off) ? sc[tid - off] : 0;
        __syncthreads(); sc[tid] += t; __syncthreads();
    }
    int run = sc[tid] - tot;
    lcnt[4 * tid]     = run;
    lcnt[4 * tid + 1] = run + c0;
    lcnt[4 * tid + 2] = run + c0 + c1;
    lcnt[4 * tid + 3] = run + c0 + c1 + c2;
    __syncthreads();
    // pass 2: scatter into LDS at local sorted position
    #pragma unroll
    for (int k = 0; k < 16; ++k) {
        if (bk[k] >= 0) {
            int slot = lcnt[bk[k]] + rk[k];
            buf[slot] = val[k];
            bkt[slot] = (unsigned short)bk[k];
        }
    }
    __syncthreads();
    // pass 3: stream out; consecutive slots in a bucket -> consecutive global
    int total = E - base; if (total > 4096) total = 4096;
    for (int t = tid; t < total; t += 256) {
        int bb = bkt[t];
        part[lcur[bb] + (t - lcnt[bb])] = buf[t];
    }
}

// Block-per-bucket second sort, R27: LDS-staged OUTPUT (96KB dynamic).
__launch_bounds__(512)
__global__ void k_sort2(const int* __restrict__ part, const int* __restrict__ bucketStart,
                        int* __restrict__ srcSorted, int* __restrict__ start,
                        float* __restrict__ dinv, int N, int B) {
    __shared__ int cnt[512];
    __shared__ int s[512];
    __shared__ int cur[512];
    extern __shared__ int sbuf[];   // 24576 ints (96 KB dynamic)
    int tid = threadIdx.x, b = blockIdx.x;
    cnt[tid] = 0;
    __syncthreads();
    int lo = bucketStart[b], hi = bucketStart[b + 1];
    int tot = hi - lo;
    for (int idx = lo + tid; idx < hi; idx += 512)
        atomicAdd(&cnt[(part[idx] >> 17) & 511], 1);
    __syncthreads();
    int v = cnt[tid];
    s[tid] = v; __syncthreads();
    for (int off = 1; off < 512; off <<= 1) {
        int t = (tid >= off) ? s[tid - off] : 0;
        __syncthreads(); s[tid] += t; __syncthreads();
    }
    int loc = s[tid] - v;          // bucket-local exclusive-scan position
    cur[tid] = loc;
    int node = b * 512 + tid;
    if (node < N) {
        start[node] = lo + loc;
        dinv[node] = rsqrtf((float)(v + 1));  // +1 self-loop
    }
    if (b == 0 && tid == 0) start[N] = bucketStart[B];  // = E
    __syncthreads();
    if (tot <= 24576) {
        for (int idx = lo + tid; idx < hi; idx += 512) {
            int pw = part[idx];
            int pos = atomicAdd(&cur[(pw >> 17) & 511], 1);  // LDS atomic
            sbuf[pos] = pw & 0x1FFFF;
        }
        __syncthreads();
        for (int t = tid; t < tot; t += 512)
            srcSorted[lo + t] = sbuf[t];
    } else {
        for (int idx = lo + tid; idx < hi; idx += 512) {
            int pw = part[idx];
            int pos = atomicAdd(&cur[(pw >> 17) & 511], 1);
            srcSorted[lo + pos] = pw & 0x1FFFF;
        }
    }
}

// Merged MFMA GEMM, LDS-free: hb[row][n] = bf16((x@W1)[row][n] * dinv[row]).
// R21: f32 path software-pipelined across row-blocks. R29: grid 768
// (3 blocks/CU; R5 showed 24.6% occupancy = 2-block grid cap).
__launch_bounds__(256)
__global__ void k_gemm(const void* x, const unsigned short* __restrict__ wT,
                       const unsigned short* __restrict__ wTh,
                       const unsigned short* __restrict__ wTl,
                       const float* __restrict__ dinv,
                       unsigned short* __restrict__ hb, const int* flags, int N) {
    int tid = threadIdx.x;
    int lane = tid & 63, wv = tid >> 6;
    int q = lane >> 4, r = lane & 15;
    int gw = blockIdx.x * 4 + wv;
    int nW = gridDim.x * 4;
    int RB = (N + 15) >> 4;
    int isbf = flags[1];
    if (isbf) {
        const unsigned short* xb = (const unsigned short*)x;
        for (int rb = gw; rb < RB; rb += nW) {
            int row0 = rb * 16;
            int arow = row0 + r;
            s8_t a[4];
            #pragma unroll
            for (int kk = 0; kk < 4; ++kk)
                a[kk] = (arow < N)
                    ? *(const s8_t*)&xb[(long long)arow * 128 + kk * 32 + q * 8]
                    : (s8_t)(short)0;
            f4_t acc[4];
            #pragma unroll
            for (int nt = 0; nt < 4; ++nt) acc[nt] = (f4_t){0.f, 0.f, 0.f, 0.f};
            #pragma unroll
            for (int nt = 0; nt < 4; ++nt) {
                #pragma unroll
                for (int kk = 0; kk < 4; ++kk) {
                    s8_t b = *(const s8_t*)&wT[(nt * 16 + r) * 128 + kk * 32 + q * 8];
                    acc[nt] = __builtin_amdgcn_mfma_f32_16x16x32_bf16(a[kk], b, acc[nt], 0, 0, 0);
                }
            }
            #pragma unroll
            for (int reg = 0; reg < 4; ++reg) {
                int row = row0 + q * 4 + reg;
                if (row < N) {
                    float dv = dinv[row];
                    #pragma unroll
                    for (int nt = 0; nt < 4; ++nt)
                        hb[(long long)row * 64 + nt * 16 + r] = f2bf(acc[nt][reg] * dv);
                }
            }
        }
    } else {
        const float* xf = (const float*)x;
        f4_t cx0[4], cx1[4];
        int rb = gw;
        if (rb < RB) {
            int arow = rb * 16 + r;
            #pragma unroll
            for (int kk = 0; kk < 4; ++kk) {
                if (arow < N) {
                    const float* p = &xf[(long long)arow * 128 + kk * 32 + q * 8];
                    cx0[kk] = *(const f4_t*)p;
                    cx1[kk] = *(const f4_t*)(p + 4);
                } else {
                    cx0[kk] = (f4_t){0.f, 0.f, 0.f, 0.f};
                    cx1[kk] = (f4_t){0.f, 0.f, 0.f, 0.f};
                }
            }
        }
        for (; rb < RB; rb += nW) {
            // 1. convert current x to bf16 hi/lo (frees cx for the prefetch)
            s8_t ah[4], al[4];
            #pragma unroll
            for (int kk = 0; kk < 4; ++kk) {
                #pragma unroll
                for (int j = 0; j < 4; ++j) {
                    union { float f; unsigned int u; } c0, h0, r0, c1, h1, r1;
                    c0.f = cx0[kk][j];
                    h0.u = c0.u & 0xffff0000u;
                    ah[kk][j] = (short)(c0.u >> 16);
                    r0.f = c0.f - h0.f;
                    al[kk][j] = (short)(r0.u >> 16);
                    c1.f = cx1[kk][j];
                    h1.u = c1.u & 0xffff0000u;
                    ah[kk][4 + j] = (short)(c1.u >> 16);
                    r1.f = c1.f - h1.f;
                    al[kk][4 + j] = (short)(r1.u >> 16);
                }
            }
            // 2. issue next row-block's loads (fly under the MFMA below)
            int rbn = rb + nW;
            if (rbn < RB) {
                int arow = rbn * 16 + r;
                #pragma unroll
                for (int kk = 0; kk < 4; ++kk) {
                    if (arow < N) {
                        const float* p = &xf[(long long)arow * 128 + kk * 32 + q * 8];
                        cx0[kk] = *(const f4_t*)p;
                        cx1[kk] = *(const f4_t*)(p + 4);
                    } else {
                        cx0[kk] = (f4_t){0.f, 0.f, 0.f, 0.f};
                        cx1[kk] = (f4_t){0.f, 0.f, 0.f, 0.f};
                    }
                }
            }
            // 3. MFMA (wT tables L1/L2-resident)
            f4_t acc[4];
            #pragma unroll
            for (int nt = 0; nt < 4; ++nt) acc[nt] = (f4_t){0.f, 0.f, 0.f, 0.f};
            #pragma unroll
            for (int nt = 0; nt < 4; ++nt) {
                #pragma unroll
                for (int kk = 0; kk < 4; ++kk) {
                    s8_t bh = *(const s8_t*)&wTh[(nt * 16 + r) * 128 + kk * 32 + q * 8];
                    s8_t bl = *(const s8_t*)&wTl[(nt * 16 + r) * 128 + kk * 32 + q * 8];
                    acc[nt] = __builtin_amdgcn_mfma_f32_16x16x32_bf16(ah[kk], bh, acc[nt], 0, 0, 0);
                    acc[nt] = __builtin_amdgcn_mfma_f32_16x16x32_bf16(al[kk], bh, acc[nt], 0, 0, 0);
                    acc[nt] = __builtin_amdgcn_mfma_f32_16x16x32_bf16(ah[kk], bl, acc[nt], 0, 0, 0);
                }
            }
            // 4. store
            int row0 = rb * 16;
            #pragma unroll
            for (int reg = 0; reg < 4; ++reg) {
                int row = row0 + q * 4 + reg;
                if (row < N) {
                    float dv = dinv[row];
                    #pragma unroll
                    for (int nt = 0; nt < 4; ++nt)
                        hb[(long long)row * 64 + nt * 16 + r] = f2bf(acc[nt][reg] * dv);
                }
            }
        }
    }
}

// Layer-1 aggregation + epilogue, wave-per-node, register accumulation.
// R15-exact structure (89us @ 3.4 TB/s = HW wall). FROZEN.
__launch_bounds__(256)
__global__ void k_agg1(const unsigned short* __restrict__ hb,
                       const float* __restrict__ dinv,
                       const int* __restrict__ start,
                       const int* __restrict__ srcSorted,
                       const void* b1, const void* W2, float* __restrict__ sbuf2,
                       const int* flags, int N) {
    int lane = threadIdx.x & 63;
    int node = (blockIdx.x * blockDim.x + threadIdx.x) >> 6;
    if (node >= N) return;
    int isbf = flags[1];
    float di = dinv[node];
    int base = start[node], cnt = start[node + 1] - base;
    float acc = bf2f(hb[(long long)node * 64 + lane]);  // self-loop: *di in epilogue
    for (int c = 0; c < cnt; c += 64) {
        int t = c + lane;
        int sidx = (t < cnt) ? srcSorted[base + t] : 0;
        int m = cnt - c; if (m > 64) m = 64;
        int t2 = 0;
        for (; t2 + 16 <= m; t2 += 16) {
            int s0  = __shfl(sidx, t2 + 0),  s1  = __shfl(sidx, t2 + 1);
            int s2  = __shfl(sidx, t2 + 2),  s3  = __shfl(sidx, t2 + 3);
            int s4  = __shfl(sidx, t2 + 4),  s5  = __shfl(sidx, t2 + 5);
            int s6  = __shfl(sidx, t2 + 6),  s7  = __shfl(sidx, t2 + 7);
            int s8  = __shfl(sidx, t2 + 8),  s9  = __shfl(sidx, t2 + 9);
            int s10 = __shfl(sidx, t2 + 10), s11 = __shfl(sidx, t2 + 11);
            int s12 = __shfl(sidx, t2 + 12), s13 = __shfl(sidx, t2 + 13);
            int s14 = __shfl(sidx, t2 + 14), s15 = __shfl(sidx, t2 + 15);
            unsigned short v0  = hb[(long long)s0  * 64 + lane];
            unsigned short v1  = hb[(long long)s1  * 64 + lane];
            unsigned short v2  = hb[(long long)s2  * 64 + lane];
            unsigned short v3  = hb[(long long)s3  * 64 + lane];
            unsigned short v4  = hb[(long long)s4  * 64 + lane];
            unsigned short v5  = hb[(long long)s5  * 64 + lane];
            unsigned short v6  = hb[(long long)s6  * 64 + lane];
            unsigned short v7  = hb[(long long)s7  * 64 + lane];
            unsigned short v8  = hb[(long long)s8  * 64 + lane];
            unsigned short v9  = hb[(long long)s9  * 64 + lane];
            unsigned short v10 = hb[(long long)s10 * 64 + lane];
            unsigned short v11 = hb[(long long)s11 * 64 + lane];
            unsigned short v12 = hb[(long long)s12 * 64 + lane];
            unsigned short v13 = hb[(long long)s13 * 64 + lane];
            unsigned short v14 = hb[(long long)s14 * 64 + lane];
            unsigned short v15 = hb[(long long)s15 * 64 + lane];
            acc += bf2f(v0);  acc += bf2f(v1);  acc += bf2f(v2);  acc += bf2f(v3);
            acc += bf2f(v4);  acc += bf2f(v5);  acc += bf2f(v6);  acc += bf2f(v7);
            acc += bf2f(v8);  acc += bf2f(v9);  acc += bf2f(v10); acc += bf2f(v11);
            acc += bf2f(v12); acc += bf2f(v13); acc += bf2f(v14); acc += bf2f(v15);
        }
        for (; t2 + 8 <= m; t2 += 8) {
            int s0 = __shfl(sidx, t2 + 0), s1 = __shfl(sidx, t2 + 1);
            int s2 = __shfl(sidx, t2 + 2), s3 = __shfl(sidx, t2 + 3);
            int s4 = __shfl(sidx, t2 + 4), s5 = __shfl(sidx, t2 + 5);
            int s6 = __shfl(sidx, t2 + 6), s7 = __shfl(sidx, t2 + 7);
            unsigned short v0 = hb[(long long)s0 * 64 + lane];
            unsigned short v1 = hb[(long long)s1 * 64 + lane];
            unsigned short v2 = hb[(long long)s2 * 64 + lane];
            unsigned short v3 = hb[(long long)s3 * 64 + lane];
            unsigned short v4 = hb[(long long)s4 * 64 + lane];
            unsigned short v5 = hb[(long long)s5 * 64 + lane];
            unsigned short v6 = hb[(long long)s6 * 64 + lane];
            unsigned short v7 = hb[(long long)s7 * 64 + lane];
            acc += bf2f(v0); acc += bf2f(v1); acc += bf2f(v2); acc += bf2f(v3);
            acc += bf2f(v4); acc += bf2f(v5); acc += bf2f(v6); acc += bf2f(v7);
        }
        for (; t2 < m; ++t2) {
            int s0 = __shfl(sidx, t2);
            acc += bf2f(hb[(long long)s0 * 64 + lane]);
        }
    }
    float v = acc * di + loadF(b1, lane, isbf);
    v = fmaxf(v, 0.f);
    float p = v * loadF(W2, lane, isbf);
    #pragma unroll
    for (int o = 32; o >= 1; o >>= 1) p += __shfl_xor(p, o);
    if (lane == 0) sbuf2[node] = p * di;
}

// Layer-2: out[i] = (sum_src sbuf2[src] + sbuf2[i]) * dinv[i] + b2.
__launch_bounds__(256)
__global__ void k_agg2(const float* __restrict__ sbuf2, const float* __restrict__ dinv,
                       const int* __restrict__ start,
                       const int* __restrict__ srcSorted,
                       const void* b2, void* out, const int* flags, int N) {
    int lane = threadIdx.x & 63;
    int node = (blockIdx.x * blockDim.x + threadIdx.x) >> 6;
    if (node >= N) return;
    int isbf = flags[1];
    float di = dinv[node];
    int base = start[node], cnt = start[node + 1] - base;
    float part = 0.f;
    for (int t = lane; t < cnt; t += 64) part += sbuf2[srcSorted[base + t]];
    #pragma unroll
    for (int o = 32; o >= 1; o >>= 1) part += __shfl_xor(part, o);
    if (lane == 0) {
        float o_ = (part + sbuf2[node]) * di + loadF(b2, 0, isbf);
        if (isbf) ((unsigned short*)out)[node] = f2bf(o_);
        else      ((float*)out)[node] = o_;
    }
}

extern "C" void kernel_launch(void* const* d_in, const int* in_sizes, int n_in,
                              void* d_out, int out_size, void* d_ws, size_t ws_size,
                              hipStream_t stream) {
    const void* x  = d_in[0];
    const void* e  = d_in[1];
    const void* W1 = d_in[2];
    const void* b1 = d_in[3];
    const void* W2 = d_in[4];
    const void* b2 = d_in[5];
    int N = in_sizes[0] / 128;     // 100000
    int E = in_sizes[1] / 2;       // 3200000
    int B  = (N + 511) / 512;      // 196 buckets of 512 nodes
    int HB = (E + 4095) / 4096;    // 782 hist blocks
    int M  = B * HB;               // 153,272
    int nP = (M + 255) / 256;      // 599 scanA blocks
    int NB = B * 512;              // 100,352 padded nodes
    int EP = ((E + 255) / 256) * 256;

    // Workspace (~27 MB; 40.4 MB proven safe, 52.8 MB crashes):
    int*   wsI         = (int*)d_ws;
    int*   flags       = wsI;                              // 256
    unsigned short* wT  = (unsigned short*)(wsI + 256);    // 8192 ushorts (16KB)
    unsigned short* wTh = (unsigned short*)(wsI + 256 + 4096);  // 8192 ushorts
    unsigned short* wTl = (unsigned short*)(wsI + 256 + 8192);  // 8192 ushorts
    int*   histT       = wsI + 256 + 12288;                // M rounded
    int*   partial     = histT + ((M + 255) / 256) * 256;  // nP rounded
    int*   bucketStart = partial + ((nP + 255) / 256) * 256;  // B+1 -> 1040
    float* dinv        = (float*)(bucketStart + 1040);     // NB
    float* sbuf2       = dinv + NB;                        // NB
    int*   start       = (int*)(sbuf2 + NB);               // NB + 256
    int*   srcSorted   = start + NB + 256;                 // EP
    int*   part        = srcSorted + EP;                   // EP (12.8 MB)
    unsigned short* hb = (unsigned short*)part;            // N*64 bf16, ALIASES part

    hipLaunchKernelGGL(k_hist, dim3(HB), dim3(256), 0, stream,
                       e, x, W1, flags, wT, wTh, wTl, histT, E, B, HB);
    hipLaunchKernelGGL(k_scanA, dim3(nP), dim3(256), 0, stream, histT, partial, M);
    hipLaunchKernelGGL(k_scanC, dim3(nP), dim3(256), 0, stream,
                       histT, partial, bucketStart, M, HB, B, E);
    hipLaunchKernelGGL(k_part, dim3(HB), dim3(256), 0, stream, e, histT, part, flags, E, B, HB);
    hipLaunchKernelGGL(k_sort2, dim3(B), dim3(512), 98304, stream,
                       part, bucketStart, srcSorted, start, dinv, N, B);
    hipLaunchKernelGGL(k_gemm, dim3(768), dim3(256), 0, stream,
                       x, wT, wTh, wTl, dinv, hb, flags, N);
    hipLaunchKernelGGL(k_agg1, dim3((N + 3) / 4), dim3(256), 0, stream,
                       hb, dinv, start, srcSorted, b1, W2, sbuf2, flags, N);
    hipLaunchKernelGGL(k_agg2, dim3((N + 3) / 4), dim3(256), 0, stream,
                       sbuf2, dinv, start, srcSorted, b2, d_out, flags, N);
}

// Round 16
// 285.318 us; speedup vs baseline: 1.0191x; 1.0191x over previous
//
#include <hip/hip_runtime.h>
#include <hip/hip_bf16.h>

// GCN 2-layer on MI355X — global-atomic-free CSR build + register-acc aggregation.
// R5-R15: see git history. agg1 FROZEN at 89us = HW wall (random 128B
//      gathers, 12.8MB table, L2-miss path 3.4 TB/s; 10x reproduced).
// R16-R19: QUARTERING ARC abandoned (L2-resident 32B gathers lose).
// R20: nontemporal store REGRESSED +58us. Reverted.
// R21: pipelined k_gemm, grid 512. 313us.
// R22: k_part LDS-staged counting sort. 302.6us.
// R23: harness ws-poison fill = 42us/iter; launch boundary ~3-7us.
// R24: merged detect+prep, eliminated scanB. 297.8us.
// R25/R26: block-local part + binary-search sort2 REGRESSED; measured
//      sort2 srcSorted scatter = 95MB writes for 12.8MB payload.
// R27: sort2 output staged in 96KB dynamic LDS (1.0x write amp). 286.2us.
// R28: int4 edge loads in hist/part (G13). 284.2us BEST.
// R29: REGRESSED +6.6us (fold detect into hist + gemm grid 768: the fold
//      put detect in all 782 blocks' path and prep serialized into block 1;
//      grid 768 cut per-wave trips 3->2, weakening the R21 pipeline).
// R30: REVERT to R28 exact. agg1 at measured HW wall; fill is harness's;
//      all sub-fill kernels carry counter-verified fixes (R21/R22/R24/
//      R27/R28). Both remaining evidence-backed levers (R29) came back
//      negative -> R28 is the anchor configuration.

typedef short s8_t __attribute__((ext_vector_type(8)));
typedef float f4_t __attribute__((ext_vector_type(4)));

__device__ __forceinline__ float bf2f(unsigned short u) {
    union { unsigned int u; float f; } c; c.u = ((unsigned int)u) << 16; return c.f;
}
__device__ __forceinline__ unsigned short f2bf(float f) {
    union { float f; unsigned int u; } c; c.f = f;
    unsigned int u = c.u;
    unsigned int r = (u + 0x7fffu + ((u >> 16) & 1u)) >> 16;  // round-nearest-even
    return (unsigned short)r;
}
__device__ __forceinline__ float loadF(const void* p, int i, int isbf) {
    return isbf ? bf2f(((const unsigned short*)p)[i]) : ((const float*)p)[i];
}
__device__ __forceinline__ int edgeIdx(const void* e, long long i, int is64) {
    return is64 ? (int)((const long long*)e)[i] : ((const int*)e)[i];
}
// R28: load 4 consecutive edge indices starting at element i (i % 4 == 0).
__device__ __forceinline__ void edgeIdx4(const void* e, long long i, int is64,
                                         int& v0, int& v1, int& v2, int& v3) {
    if (is64) {
        const int4* p = (const int4*)((const long long*)e + i);
        int4 a = p[0], b = p[1];           // 2 long longs per int4 (LE: low word = .x/.z)
        v0 = a.x; v1 = a.z; v2 = b.x; v3 = b.z;
    } else {
        int4 v = *(const int4*)((const int*)e + i);
        v0 = v.x; v1 = v.y; v2 = v.z; v3 = v.w;
    }
}

// Merged detect + weight prep (R24). Wave 0 detects, block preps weights.
__global__ void k_detect_prep(const void* e, const void* x, const void* W1,
                              int* flags, unsigned short* __restrict__ wT,
                              unsigned short* __restrict__ wTh,
                              unsigned short* __restrict__ wTl) {
    __shared__ int sfl;
    int tid = threadIdx.x;   // 256 threads
    if (tid < 64) {
        unsigned int ew = ((const unsigned int*)e)[2 * tid + 1];
        unsigned long long nz = __ballot(ew != 0);
        unsigned int xw = ((const unsigned int*)x)[tid];
        unsigned int low = xw & 0xffffu;
        unsigned int e8 = (low >> 7) & 0xffu;
        bool plaus = (low == 0u) || (e8 >= 110u && e8 <= 135u);
        unsigned long long pl = __ballot(plaus);
        if (tid == 0) {
            flags[0] = (nz == 0ull) ? 1 : 0;
            int isbf = (__popcll(pl) > 32) ? 1 : 0;
            flags[1] = isbf;
            sfl = isbf;
        }
    }
    __syncthreads();
    int isbf = sfl;
    if (isbf) {
        const unsigned short* w = (const unsigned short*)W1;
        for (int idx = tid; idx < 128 * 64; idx += 256) {
            int k = idx >> 6, n = idx & 63;
            wT[n * 128 + k] = w[idx];
        }
    } else {
        const float* w = (const float*)W1;
        for (int idx = tid; idx < 128 * 64; idx += 256) {
            int k = idx >> 6, n = idx & 63;
            float v = w[idx];
            unsigned short h = f2bf(v);
            wTh[n * 128 + k] = h;
            wTl[n * 128 + k] = f2bf(v - bf2f(h));
        }
    }
}

// Per-block LDS histogram over B coarse buckets (dst>>9); hist[bucket][block].
// R28: int4 dst loads (4 edges/instr) on full blocks.
__launch_bounds__(256)
__global__ void k_hist(const void* e, int* __restrict__ histT, const int* flags,
                       int E, int B, int HB) {
    __shared__ int hist[1024];
    int tid = threadIdx.x;
    int is64 = flags[0];
    for (int f = tid; f < B; f += 256) hist[f] = 0;
    __syncthreads();
    int base = blockIdx.x * 4096;
    if (base + 4096 <= E) {
        #pragma unroll
        for (int k4 = 0; k4 < 4; ++k4) {
            int i = base + (k4 * 256 + tid) * 4;
            int d0, d1, d2, d3;
            edgeIdx4(e, (long long)E + i, is64, d0, d1, d2, d3);
            atomicAdd(&hist[d0 >> 9], 1);
            atomicAdd(&hist[d1 >> 9], 1);
            atomicAdd(&hist[d2 >> 9], 1);
            atomicAdd(&hist[d3 >> 9], 1);
        }
    } else {
        #pragma unroll
        for (int k = 0; k < 16; ++k) {
            int i = base + k * 256 + tid;
            if (i < E) {
                int d = edgeIdx(e, (long long)E + i, is64);
                atomicAdd(&hist[d >> 9], 1);
            }
        }
    }
    __syncthreads();
    for (int f = tid; f < B; f += 256)
        histT[(long long)f * HB + blockIdx.x] = hist[f];
}

// Exclusive scan over M = B*HB ints, level A. partial[b] = block sum (raw).
__global__ void k_scanA(int* __restrict__ data, int* __restrict__ partial, int M) {
    __shared__ int s[256];
    int tid = threadIdx.x;
    int i = blockIdx.x * 256 + tid;
    int v = (i < M) ? data[i] : 0;
    s[tid] = v; __syncthreads();
    for (int off = 1; off < 256; off <<= 1) {
        int t = (tid >= off) ? s[tid - off] : 0;
        __syncthreads(); s[tid] += t; __syncthreads();
    }
    if (i < M) data[i] = s[tid] - v;
    if (tid == 255) partial[blockIdx.x] = s[255];
}

// R24 level C (scanB eliminated): each block recomputes its own base =
// sum(partial[0..bb)) via strided loads + LDS tree reduce (<=599 ints),
// then adds it and extracts bucketStart.
__global__ void k_scanC(int* __restrict__ data, const int* __restrict__ partial,
                        int* __restrict__ bucketStart, int M, int HB, int B, int E) {
    __shared__ int red[256];
    int tid = threadIdx.x;
    int bb = blockIdx.x;
    int s = 0;
    for (int j = tid; j < bb; j += 256) s += partial[j];
    red[tid] = s; __syncthreads();
    for (int off = 128; off > 0; off >>= 1) {
        if (tid < off) red[tid] += red[tid + off];
        __syncthreads();
    }
    int base = red[0];
    int f = bb * 256 + tid;
    if (f < M) {
        int val = data[f] + base;
        data[f] = val;
        int q = f / HB;
        if (f - q * HB == 0) bucketStart[q] = val;
    }
    if (f == 0) bucketStart[B] = E;
}

// Partition (R22): LDS-staged counting sort per block.
// R28: int4 src+dst loads (4 edges / 2 instrs) on full blocks.
// part[pos] = src | (dstLocal << 17)   (requires N <= 2^17).
__launch_bounds__(256)
__global__ void k_part(const void* e, const int* __restrict__ histT,
                       int* __restrict__ part, const int* flags,
                       int E, int B, int HB) {
    __shared__ int lcur[1024];          // global scanned base per bucket
    __shared__ int lcnt[1024];          // local count -> local start (in place)
    __shared__ int sc[256];             // scan partials
    __shared__ int buf[4096];           // staged edge words
    __shared__ unsigned short bkt[4096];// bucket id per staged slot
    int tid = threadIdx.x;
    int is64 = flags[0];
    for (int f = tid; f < 1024; f += 256) {
        lcur[f] = (f < B) ? histT[(long long)f * HB + blockIdx.x] : 0;
        lcnt[f] = 0;
    }
    __syncthreads();
    int base = blockIdx.x * 4096;
    int val[16], bk[16], rk[16];
    if (base + 4096 <= E) {
        #pragma unroll
        for (int k4 = 0; k4 < 4; ++k4) {
            int i = base + (k4 * 256 + tid) * 4;
            int s0, s1, s2, s3, d0, d1, d2, d3;
            edgeIdx4(e, (long long)i, is64, s0, s1, s2, s3);
            edgeIdx4(e, (long long)E + i, is64, d0, d1, d2, d3);
            val[k4 * 4 + 0] = s0 | ((d0 & 511) << 17); bk[k4 * 4 + 0] = d0 >> 9;
            val[k4 * 4 + 1] = s1 | ((d1 & 511) << 17); bk[k4 * 4 + 1] = d1 >> 9;
            val[k4 * 4 + 2] = s2 | ((d2 & 511) << 17); bk[k4 * 4 + 2] = d2 >> 9;
            val[k4 * 4 + 3] = s3 | ((d3 & 511) << 17); bk[k4 * 4 + 3] = d3 >> 9;
            rk[k4 * 4 + 0] = atomicAdd(&lcnt[bk[k4 * 4 + 0]], 1);
            rk[k4 * 4 + 1] = atomicAdd(&lcnt[bk[k4 * 4 + 1]], 1);
            rk[k4 * 4 + 2] = atomicAdd(&lcnt[bk[k4 * 4 + 2]], 1);
            rk[k4 * 4 + 3] = atomicAdd(&lcnt[bk[k4 * 4 + 3]], 1);
        }
    } else {
        #pragma unroll
        for (int k = 0; k < 16; ++k) {
            int i = base + k * 256 + tid;
            if (i < E) {
                int s = edgeIdx(e, i, is64);
                int d = edgeIdx(e, (long long)E + i, is64);
                val[k] = s | ((d & 511) << 17);
                bk[k] = d >> 9;
                rk[k] = atomicAdd(&lcnt[bk[k]], 1);
            } else {
                bk[k] = -1;
            }
        }
    }
    __syncthreads();
    // in-place exclusive scan of lcnt[0..1023] (4 elems/thread + 256-scan)
    int c0 = lcnt[4 * tid], c1 = lcnt[4 * tid + 1];
    int c2 = lcnt[4 * tid + 2], c3 = lcnt[4 * tid + 3];
    int tot = c0 + c1 + c2 + c3;
    sc[tid] = tot; __syncthreads();
    for (int off = 1; off < 256; off <<= 1) {
        int t = (tid >= off) ? sc[tid - off] : 0;
        __syncthreads(); sc[tid] += t; __syncthreads();
    }
    int run = sc[tid] - tot;
    lcnt[4 * tid]     = run;
    lcnt[4 * tid + 1] = run + c0;
    lcnt[4 * tid + 2] = run + c0 + c1;
    lcnt[4 * tid + 3] = run + c0 + c1 + c2;
    __syncthreads();
    // pass 2: scatter into LDS at local sorted position
    #pragma unroll
    for (int k = 0; k < 16; ++k) {
        if (bk[k] >= 0) {
            int slot = lcnt[bk[k]] + rk[k];
            buf[slot] = val[k];
            bkt[slot] = (unsigned short)bk[k];
        }
    }
    __syncthreads();
    // pass 3: stream out; consecutive slots in a bucket -> consecutive global
    int total = E - base; if (total > 4096) total = 4096;
    for (int t = tid; t < total; t += 256) {
        int bb = bkt[t];
        part[lcur[bb] + (t - lcnt[bb])] = buf[t];
    }
}

// Block-per-bucket second sort, R27: LDS-staged OUTPUT (96KB dynamic).
__launch_bounds__(512)
__global__ void k_sort2(const int* __restrict__ part, const int* __restrict__ bucketStart,
                        int* __restrict__ srcSorted, int* __restrict__ start,
                        float* __restrict__ dinv, int N, int B) {
    __shared__ int cnt[512];
    __shared__ int s[512];
    __shared__ int cur[512];
    extern __shared__ int sbuf[];   // 24576 ints (96 KB dynamic)
    int tid = threadIdx.x, b = blockIdx.x;
    cnt[tid] = 0;
    __syncthreads();
    int lo = bucketStart[b], hi = bucketStart[b + 1];
    int tot = hi - lo;
    for (int idx = lo + tid; idx < hi; idx += 512)
        atomicAdd(&cnt[(part[idx] >> 17) & 511], 1);
    __syncthreads();
    int v = cnt[tid];
    s[tid] = v; __syncthreads();
    for (int off = 1; off < 512; off <<= 1) {
        int t = (tid >= off) ? s[tid - off] : 0;
        __syncthreads(); s[tid] += t; __syncthreads();
    }
    int loc = s[tid] - v;          // bucket-local exclusive-scan position
    cur[tid] = loc;
    int node = b * 512 + tid;
    if (node < N) {
        start[node] = lo + loc;
        dinv[node] = rsqrtf((float)(v + 1));  // +1 self-loop
    }
    if (b == 0 && tid == 0) start[N] = bucketStart[B];  // = E
    __syncthreads();
    if (tot <= 24576) {
        for (int idx = lo + tid; idx < hi; idx += 512) {
            int pw = part[idx];
            int pos = atomicAdd(&cur[(pw >> 17) & 511], 1);  // LDS atomic
            sbuf[pos] = pw & 0x1FFFF;
        }
        __syncthreads();
        for (int t = tid; t < tot; t += 512)
            srcSorted[lo + t] = sbuf[t];
    } else {
        for (int idx = lo + tid; idx < hi; idx += 512) {
            int pw = part[idx];
            int pos = atomicAdd(&cur[(pw >> 17) & 511], 1);
            srcSorted[lo + pos] = pw & 0x1FFFF;
        }
    }
}

// Merged MFMA GEMM, LDS-free: hb[row][n] = bf16((x@W1)[row][n] * dinv[row]).
// R21: f32 path software-pipelined across row-blocks. Grid 512.
__launch_bounds__(256)
__global__ void k_gemm(const void* x, const unsigned short* __restrict__ wT,
                       const unsigned short* __restrict__ wTh,
                       const unsigned short* __restrict__ wTl,
                       const float* __restrict__ dinv,
                       unsigned short* __restrict__ hb, const int* flags, int N) {
    int tid = threadIdx.x;
    int lane = tid & 63, wv = tid >> 6;
    int q = lane >> 4, r = lane & 15;
    int gw = blockIdx.x * 4 + wv;
    int nW = gridDim.x * 4;
    int RB = (N + 15) >> 4;
    int isbf = flags[1];
    if (isbf) {
        const unsigned short* xb = (const unsigned short*)x;
        for (int rb = gw; rb < RB; rb += nW) {
            int row0 = rb * 16;
            int arow = row0 + r;
            s8_t a[4];
            #pragma unroll
            for (int kk = 0; kk < 4; ++kk)
                a[kk] = (arow < N)
                    ? *(const s8_t*)&xb[(long long)arow * 128 + kk * 32 + q * 8]
                    : (s8_t)(short)0;
            f4_t acc[4];
            #pragma unroll
            for (int nt = 0; nt < 4; ++nt) acc[nt] = (f4_t){0.f, 0.f, 0.f, 0.f};
            #pragma unroll
            for (int nt = 0; nt < 4; ++nt) {
                #pragma unroll
                for (int kk = 0; kk < 4; ++kk) {
                    s8_t b = *(const s8_t*)&wT[(nt * 16 + r) * 128 + kk * 32 + q * 8];
                    acc[nt] = __builtin_amdgcn_mfma_f32_16x16x32_bf16(a[kk], b, acc[nt], 0, 0, 0);
                }
            }
            #pragma unroll
            for (int reg = 0; reg < 4; ++reg) {
                int row = row0 + q * 4 + reg;
                if (row < N) {
                    float dv = dinv[row];
                    #pragma unroll
                    for (int nt = 0; nt < 4; ++nt)
                        hb[(long long)row * 64 + nt * 16 + r] = f2bf(acc[nt][reg] * dv);
                }
            }
        }
    } else {
        const float* xf = (const float*)x;
        f4_t cx0[4], cx1[4];
        int rb = gw;
        if (rb < RB) {
            int arow = rb * 16 + r;
            #pragma unroll
            for (int kk = 0; kk < 4; ++kk) {
                if (arow < N) {
                    const float* p = &xf[(long long)arow * 128 + kk * 32 + q * 8];
                    cx0[kk] = *(const f4_t*)p;
                    cx1[kk] = *(const f4_t*)(p + 4);
                } else {
                    cx0[kk] = (f4_t){0.f, 0.f, 0.f, 0.f};
                    cx1[kk] = (f4_t){0.f, 0.f, 0.f, 0.f};
                }
            }
        }
        for (; rb < RB; rb += nW) {
            // 1. convert current x to bf16 hi/lo (frees cx for the prefetch)
            s8_t ah[4], al[4];
            #pragma unroll
            for (int kk = 0; kk < 4; ++kk) {
                #pragma unroll
                for (int j = 0; j < 4; ++j) {
                    union { float f; unsigned int u; } c0, h0, r0, c1, h1, r1;
                    c0.f = cx0[kk][j];
                    h0.u = c0.u & 0xffff0000u;
                    ah[kk][j] = (short)(c0.u >> 16);
                    r0.f = c0.f - h0.f;
                    al[kk][j] = (short)(r0.u >> 16);
                    c1.f = cx1[kk][j];
                    h1.u = c1.u & 0xffff0000u;
                    ah[kk][4 + j] = (short)(c1.u >> 16);
                    r1.f = c1.f - h1.f;
                    al[kk][4 + j] = (short)(r1.u >> 16);
                }
            }
            // 2. issue next row-block's loads (fly under the MFMA below)
            int rbn = rb + nW;
            if (rbn < RB) {
                int arow = rbn * 16 + r;
                #pragma unroll
                for (int kk = 0; kk < 4; ++kk) {
                    if (arow < N) {
                        const float* p = &xf[(long long)arow * 128 + kk * 32 + q * 8];
                        cx0[kk] = *(const f4_t*)p;
                        cx1[kk] = *(const f4_t*)(p + 4);
                    } else {
                        cx0[kk] = (f4_t){0.f, 0.f, 0.f, 0.f};
                        cx1[kk] = (f4_t){0.f, 0.f, 0.f, 0.f};
                    }
                }
            }
            // 3. MFMA (wT tables L1/L2-resident)
            f4_t acc[4];
            #pragma unroll
            for (int nt = 0; nt < 4; ++nt) acc[nt] = (f4_t){0.f, 0.f, 0.f, 0.f};
            #pragma unroll
            for (int nt = 0; nt < 4; ++nt) {
                #pragma unroll
                for (int kk = 0; kk < 4; ++kk) {
                    s8_t bh = *(const s8_t*)&wTh[(nt * 16 + r) * 128 + kk * 32 + q * 8];
                    s8_t bl = *(const s8_t*)&wTl[(nt * 16 + r) * 128 + kk * 32 + q * 8];
                    acc[nt] = __builtin_amdgcn_mfma_f32_16x16x32_bf16(ah[kk], bh, acc[nt], 0, 0, 0);
                    acc[nt] = __builtin_amdgcn_mfma_f32_16x16x32_bf16(al[kk], bh, acc[nt], 0, 0, 0);
                    acc[nt] = __builtin_amdgcn_mfma_f32_16x16x32_bf16(ah[kk], bl, acc[nt], 0, 0, 0);
                }
            }
            // 4. store
            int row0 = rb * 16;
            #pragma unroll
            for (int reg = 0; reg < 4; ++reg) {
                int row = row0 + q * 4 + reg;
                if (row < N) {
                    float dv = dinv[row];
                    #pragma unroll
                    for (int nt = 0; nt < 4; ++nt)
                        hb[(long long)row * 64 + nt * 16 + r] = f2bf(acc[nt][reg] * dv);
                }
            }
        }
    }
}

// Layer-1 aggregation + epilogue, wave-per-node, register accumulation.
// R15-exact structure (89us @ 3.4 TB/s = HW wall). FROZEN.
__launch_bounds__(256)
__global__ void k_agg1(const unsigned short* __restrict__ hb,
                       const float* __restrict__ dinv,
                       const int* __restrict__ start,
                       const int* __restrict__ srcSorted,
                       const void* b1, const void* W2, float* __restrict__ sbuf2,
                       const int* flags, int N) {
    int lane = threadIdx.x & 63;
    int node = (blockIdx.x * blockDim.x + threadIdx.x) >> 6;
    if (node >= N) return;
    int isbf = flags[1];
    float di = dinv[node];
    int base = start[node], cnt = start[node + 1] - base;
    float acc = bf2f(hb[(long long)node * 64 + lane]);  // self-loop: *di in epilogue
    for (int c = 0; c < cnt; c += 64) {
        int t = c + lane;
        int sidx = (t < cnt) ? srcSorted[base + t] : 0;
        int m = cnt - c; if (m > 64) m = 64;
        int t2 = 0;
        for (; t2 + 16 <= m; t2 += 16) {
            int s0  = __shfl(sidx, t2 + 0),  s1  = __shfl(sidx, t2 + 1);
            int s2  = __shfl(sidx, t2 + 2),  s3  = __shfl(sidx, t2 + 3);
            int s4  = __shfl(sidx, t2 + 4),  s5  = __shfl(sidx, t2 + 5);
            int s6  = __shfl(sidx, t2 + 6),  s7  = __shfl(sidx, t2 + 7);
            int s8  = __shfl(sidx, t2 + 8),  s9  = __shfl(sidx, t2 + 9);
            int s10 = __shfl(sidx, t2 + 10), s11 = __shfl(sidx, t2 + 11);
            int s12 = __shfl(sidx, t2 + 12), s13 = __shfl(sidx, t2 + 13);
            int s14 = __shfl(sidx, t2 + 14), s15 = __shfl(sidx, t2 + 15);
            unsigned short v0  = hb[(long long)s0  * 64 + lane];
            unsigned short v1  = hb[(long long)s1  * 64 + lane];
            unsigned short v2  = hb[(long long)s2  * 64 + lane];
            unsigned short v3  = hb[(long long)s3  * 64 + lane];
            unsigned short v4  = hb[(long long)s4  * 64 + lane];
            unsigned short v5  = hb[(long long)s5  * 64 + lane];
            unsigned short v6  = hb[(long long)s6  * 64 + lane];
            unsigned short v7  = hb[(long long)s7  * 64 + lane];
            unsigned short v8  = hb[(long long)s8  * 64 + lane];
            unsigned short v9  = hb[(long long)s9  * 64 + lane];
            unsigned short v10 = hb[(long long)s10 * 64 + lane];
            unsigned short v11 = hb[(long long)s11 * 64 + lane];
            unsigned short v12 = hb[(long long)s12 * 64 + lane];
            unsigned short v13 = hb[(long long)s13 * 64 + lane];
            unsigned short v14 = hb[(long long)s14 * 64 + lane];
            unsigned short v15 = hb[(long long)s15 * 64 + lane];
            acc += bf2f(v0);  acc += bf2f(v1);  acc += bf2f(v2);  acc += bf2f(v3);
            acc += bf2f(v4);  acc += bf2f(v5);  acc += bf2f(v6);  acc += bf2f(v7);
            acc += bf2f(v8);  acc += bf2f(v9);  acc += bf2f(v10); acc += bf2f(v11);
            acc += bf2f(v12); acc += bf2f(v13); acc += bf2f(v14); acc += bf2f(v15);
        }
        for (; t2 + 8 <= m; t2 += 8) {
            int s0 = __shfl(sidx, t2 + 0), s1 = __shfl(sidx, t2 + 1);
            int s2 = __shfl(sidx, t2 + 2), s3 = __shfl(sidx, t2 + 3);
            int s4 = __shfl(sidx, t2 + 4), s5 = __shfl(sidx, t2 + 5);
            int s6 = __shfl(sidx, t2 + 6), s7 = __shfl(sidx, t2 + 7);
            unsigned short v0 = hb[(long long)s0 * 64 + lane];
            unsigned short v1 = hb[(long long)s1 * 64 + lane];
            unsigned short v2 = hb[(long long)s2 * 64 + lane];
            unsigned short v3 = hb[(long long)s3 * 64 + lane];
            unsigned short v4 = hb[(long long)s4 * 64 + lane];
            unsigned short v5 = hb[(long long)s5 * 64 + lane];
            unsigned short v6 = hb[(long long)s6 * 64 + lane];
            unsigned short v7 = hb[(long long)s7 * 64 + lane];
            acc += bf2f(v0); acc += bf2f(v1); acc += bf2f(v2); acc += bf2f(v3);
            acc += bf2f(v4); acc += bf2f(v5); acc += bf2f(v6); acc += bf2f(v7);
        }
        for (; t2 < m; ++t2) {
            int s0 = __shfl(sidx, t2);
            acc += bf2f(hb[(long long)s0 * 64 + lane]);
        }
    }
    float v = acc * di + loadF(b1, lane, isbf);
    v = fmaxf(v, 0.f);
    float p = v * loadF(W2, lane, isbf);
    #pragma unroll
    for (int o = 32; o >= 1; o >>= 1) p += __shfl_xor(p, o);
    if (lane == 0) sbuf2[node] = p * di;
}

// Layer-2: out[i] = (sum_src sbuf2[src] + sbuf2[i]) * dinv[i] + b2.
__launch_bounds__(256)
__global__ void k_agg2(const float* __restrict__ sbuf2, const float* __restrict__ dinv,
                       const int* __restrict__ start,
                       const int* __restrict__ srcSorted,
                       const void* b2, void* out, const int* flags, int N) {
    int lane = threadIdx.x & 63;
    int node = (blockIdx.x * blockDim.x + threadIdx.x) >> 6;
    if (node >= N) return;
    int isbf = flags[1];
    float di = dinv[node];
    int base = start[node], cnt = start[node + 1] - base;
    float part = 0.f;
    for (int t = lane; t < cnt; t += 64) part += sbuf2[srcSorted[base + t]];
    #pragma unroll
    for (int o = 32; o >= 1; o >>= 1) part += __shfl_xor(part, o);
    if (lane == 0) {
        float o_ = (part + sbuf2[node]) * di + loadF(b2, 0, isbf);
        if (isbf) ((unsigned short*)out)[node] = f2bf(o_);
        else      ((float*)out)[node] = o_;
    }
}

extern "C" void kernel_launch(void* const* d_in, const int* in_sizes, int n_in,
                              void* d_out, int out_size, void* d_ws, size_t ws_size,
                              hipStream_t stream) {
    const void* x  = d_in[0];
    const void* e  = d_in[1];
    const void* W1 = d_in[2];
    const void* b1 = d_in[3];
    const void* W2 = d_in[4];
    const void* b2 = d_in[5];
    int N = in_sizes[0] / 128;     // 100000
    int E = in_sizes[1] / 2;       // 3200000
    int B  = (N + 511) / 512;      // 196 buckets of 512 nodes
    int HB = (E + 4095) / 4096;    // 782 hist blocks
    int M  = B * HB;               // 153,272
    int nP = (M + 255) / 256;      // 599 scanA blocks
    int NB = B * 512;              // 100,352 padded nodes
    int EP = ((E + 255) / 256) * 256;

    // Workspace (~27 MB; 40.4 MB proven safe, 52.8 MB crashes):
    int*   wsI         = (int*)d_ws;
    int*   flags       = wsI;                              // 256
    unsigned short* wT  = (unsigned short*)(wsI + 256);    // 8192 ushorts (16KB)
    unsigned short* wTh = (unsigned short*)(wsI + 256 + 4096);  // 8192 ushorts
    unsigned short* wTl = (unsigned short*)(wsI + 256 + 8192);  // 8192 ushorts
    int*   histT       = wsI + 256 + 12288;                // M rounded
    int*   partial     = histT + ((M + 255) / 256) * 256;  // nP rounded
    int*   bucketStart = partial + ((nP + 255) / 256) * 256;  // B+1 -> 1040
    float* dinv        = (float*)(bucketStart + 1040);     // NB
    float* sbuf2       = dinv + NB;                        // NB
    int*   start       = (int*)(sbuf2 + NB);               // NB + 256
    int*   srcSorted   = start + NB + 256;                 // EP
    int*   part        = srcSorted + EP;                   // EP (12.8 MB)
    unsigned short* hb = (unsigned short*)part;            // N*64 bf16, ALIASES part

    hipLaunchKernelGGL(k_detect_prep, dim3(1), dim3(256), 0, stream,
                       e, x, W1, flags, wT, wTh, wTl);
    hipLaunchKernelGGL(k_hist, dim3(HB), dim3(256), 0, stream, e, histT, flags, E, B, HB);
    hipLaunchKernelGGL(k_scanA, dim3(nP), dim3(256), 0, stream, histT, partial, M);
    hipLaunchKernelGGL(k_scanC, dim3(nP), dim3(256), 0, stream,
                       histT, partial, bucketStart, M, HB, B, E);
    hipLaunchKernelGGL(k_part, dim3(HB), dim3(256), 0, stream, e, histT, part, flags, E, B, HB);
    hipLaunchKernelGGL(k_sort2, dim3(B), dim3(512), 98304, stream,
                       part, bucketStart, srcSorted, start, dinv, N, B);
    hipLaunchKernelGGL(k_gemm, dim3(512), dim3(256), 0, stream,
                       x, wT, wTh, wTl, dinv, hb, flags, N);
    hipLaunchKernelGGL(k_agg1, dim3((N + 3) / 4), dim3(256), 0, stream,
                       hb, dinv, start, srcSorted, b1, W2, sbuf2, flags, N);
    hipLaunchKernelGGL(k_agg2, dim3((N + 3) / 4), dim3(256), 0, stream,
                       sbuf2, dinv, start, srcSorted, b2, d_out, flags, N);
}